// Round 4
// baseline (347.807 us; speedup 1.0000x reference)
//
#include <hip/hip_runtime.h>
#include <hip/hip_bf16.h>

// S4D regressor, chunked-scan MFMA formulation.
// R4: per-wave phase independence (1 barrier, was 5), bf16 LDS state
// (19.5 KB -> 8 blocks/CU), bf16 LN tile (8 blocks/CU).
// B=32, L=4096, C=128, N=64, DEPTH=4, OUT=1.

#define BB     32
#define LL     4096
#define CC     128
#define NN     64
#define DEPTH_ 4
#define EPSV   1e-5f

typedef __attribute__((ext_vector_type(8))) short short8;
typedef __attribute__((ext_vector_type(4))) short short4v;
typedef __attribute__((ext_vector_type(4))) float f32x4;
typedef __hip_bfloat16 bf16;

#define MFMA(a, b, c) __builtin_amdgcn_mfma_f32_16x16x32_bf16(a, b, c, 0, 0, 0)

__device__ __forceinline__ bf16 tobf(float x) { return __float2bfloat16(x); }
__device__ __forceinline__ short bfbits(float x) {
    union { bf16 b; short s; } u; u.b = __float2bfloat16(x); return u.s;
}
__device__ __forceinline__ float frombits(short s) {
    return __uint_as_float(((uint)(ushort)s) << 16);
}

// ---------------------------------------------------------------------------
// P0: per (d,c,n): lam=exp(dt*A), dta=dt*A, cb2=2*C*(lam-1)/A, lamT=lam^64
// ---------------------------------------------------------------------------
__global__ __launch_bounds__(64) void p0_kernel(
    const float* __restrict__ log_dt, const float* __restrict__ A_real,
    const float* __restrict__ A_imag, const float* __restrict__ C_re,
    const float* __restrict__ C_im, float2* __restrict__ lam,
    float2* __restrict__ dta, float2* __restrict__ cb2,
    float2* __restrict__ lamT)
{
    int d = blockIdx.y, c = blockIdx.x, n = threadIdx.x;
    int idx = (d * CC + c) * NN + n;
    float dt  = expf(log_dt[d * CC + c]);
    float Ar  = -expf(A_real[idx]);
    float Ai  = A_imag[idx];
    float dtr = dt * Ar, dti = dt * Ai;
    float e   = expf(dtr);
    float lr  = e * cosf(dti), li = e * sinf(dti);
    float m    = Ar * Ar + Ai * Ai;
    float inv  = 1.0f / m;
    float numr = lr - 1.0f, numi = li;
    float br   = (numr * Ar + numi * Ai) * inv;
    float bi   = (numi * Ar - numr * Ai) * inv;
    float cre  = C_re[idx], cim = C_im[idx];
    lam[idx]  = make_float2(lr, li);
    dta[idx]  = make_float2(dtr, dti);
    cb2[idx]  = make_float2(2.0f * (cre * br - cim * bi),
                            2.0f * (cre * bi + cim * br));
    float eT = expf(64.0f * dtr);
    lamT[idx] = make_float2(eT * cosf(64.0f * dti), eT * sinf(64.0f * dti));
}

// ---------------------------------------------------------------------------
// P1: Kloc[d][c][delta] = Re sum_n cb2_n lam_n^delta   (delta = 0..63)
// ---------------------------------------------------------------------------
__global__ __launch_bounds__(64) void p1_kernel(
    const float2* __restrict__ cb2, const float2* __restrict__ lam,
    float* __restrict__ Kloc)
{
    __shared__ float st[64 * 65];
    int d = blockIdx.y, c = blockIdx.x, n = threadIdx.x;
    float2 p = cb2[(d * CC + c) * NN + n];
    float2 l = lam[(d * CC + c) * NN + n];
    for (int t = 0; t < 64; ++t) {
        st[t * 65 + n] = p.x;
        float nr = p.x * l.x - p.y * l.y;
        p.y = p.x * l.y + p.y * l.x;
        p.x = nr;
    }
    __syncthreads();
    float s = 0.0f;
#pragma unroll 16
    for (int j = 0; j < 64; ++j) s += st[n * 65 + j];
    Kloc[(d * CC + c) * 64 + n] = s;
}

// ---------------------------------------------------------------------------
// P2V: Vp packed [d][c][nf=8][ks=2][lane=64][e=8]: B[k][q]=Re/Im(lam_n^{63-k})
// ---------------------------------------------------------------------------
__global__ __launch_bounds__(256) void p2v_kernel(
    const float2* __restrict__ dta, bf16* __restrict__ Vp)
{
    int t = blockIdx.x * 256 + threadIdx.x;
    int e = t & 7, l = (t >> 3) & 63, ks = (t >> 9) & 1;
    int nf = (t >> 10) & 7, c = (t >> 13) & 127, d = t >> 20;
    int q = nf * 16 + (l & 15);
    int k = ks * 32 + (l >> 4) * 8 + e;
    int n = q >> 1;
    float2 a = dta[(d * CC + c) * NN + n];
    float p  = (float)(63 - k);
    float mag = expf(p * a.x);
    float ang = p * a.y;
    float val = (q & 1) ? mag * sinf(ang) : mag * cosf(ang);
    Vp[t] = tobf(val);
}

// ---------------------------------------------------------------------------
// P2W: W2p packed [d][c][nf=4][ks=6][lane=64][e=8]
// ---------------------------------------------------------------------------
__global__ __launch_bounds__(256) void p2w_kernel(
    const float2* __restrict__ dta, const float2* __restrict__ cb2,
    const float* __restrict__ Kloc, const float* __restrict__ Dskip,
    bf16* __restrict__ W2p)
{
    int t = blockIdx.x * 256 + threadIdx.x;
    int e = t & 7, l = (t >> 3) & 63;
    int r = t >> 9;
    int ks = r % 6; r /= 6;
    int nf = r & 3; r >>= 2;
    int c  = r & 127;
    int d  = r >> 7;
    int i = nf * 16 + (l & 15);
    int k = ks * 32 + (l >> 4) * 8 + e;
    float val;
    if (k < 64) {
        val = (k <= i) ? Kloc[(d * CC + c) * 64 + (i - k)] : 0.0f;
        if (k == i) val += Dskip[d * CC + c] + 1.0f;
    } else {
        int q = k - 64, n = q >> 1;
        float2 a  = dta[(d * CC + c) * NN + n];
        float2 cb = cb2[(d * CC + c) * NN + n];
        float p   = (float)(i + 1);
        float mag = expf(p * a.x);
        float ang = p * a.y;
        float re = mag * cosf(ang), im = mag * sinf(ang);
        float wre = cb.x * re - cb.y * im;
        float wim = cb.x * im + cb.y * re;
        val = (q & 1) ? -wim : wre;
    }
    W2p[t] = tobf(val);
}

// ---------------------------------------------------------------------------
// x [B,L,C] fp32 -> xt [B][C][L] bf16
// ---------------------------------------------------------------------------
__global__ __launch_bounds__(256) void transpose_kernel(
    const float* __restrict__ x, bf16* __restrict__ xt)
{
    __shared__ float t[64][65];
    int ct = blockIdx.x, lt = blockIdx.y, b = blockIdx.z;
    int tx = threadIdx.x & 63, ty = threadIdx.x >> 6;
    const size_t xbase = ((size_t)b * LL + (size_t)lt * 64) * CC + (size_t)ct * 64;
#pragma unroll
    for (int i = 0; i < 16; ++i)
        t[ty + 4 * i][tx] = x[xbase + (size_t)(ty + 4 * i) * CC + tx];
    __syncthreads();
    const size_t obase = ((size_t)b * CC + (size_t)ct * 64) * LL + (size_t)lt * 64;
#pragma unroll
    for (int i = 0; i < 16; ++i)
        xt[obase + (size_t)(ty + 4 * i) * LL + tx] = tobf(t[tx][ty + 4 * i]);
}

// ---------------------------------------------------------------------------
// KS: fused per-(b,c) layer kernel, 4 waves, per-wave phase independence.
// All LDS state (P_k, then Sprev overlaid) is bf16 in per-wave regions;
// only the 4-complex carry exchange crosses waves -> exactly ONE barrier.
// ---------------------------------------------------------------------------
__global__ __launch_bounds__(256, 8) void ks_kernel(
    const bf16* __restrict__ u, bf16* __restrict__ v,
    const bf16* __restrict__ Vp, const bf16* __restrict__ W2p,
    const float2* __restrict__ lamT)
{
    int b = blockIdx.x, c = blockIdx.y;
    int w = threadIdx.x >> 6, l = threadIdx.x & 63;
    const bf16* xrow = u + ((size_t)(b * CC + c)) * LL;
    const bf16* Vpc  = Vp  + (size_t)c * 8192;
    const bf16* W2c  = W2p + (size_t)c * 12288;

    __shared__ short Sl[64 * 136];     // bf16 bits: P_k, then Sprev (17.4 KB)
    __shared__ float cbuf[4 * 132];    // carry exchange (2.1 KB)

    const int m    = 16 * w + (l & 15);    // this lane's chunk (MFMA B-col)
    const int koff = (l >> 4) * 8;

    // ---- phase 1: P[m][q] = sum_k Vp[k][q] * x[m][k]  (K=64, per-wave) ----
    short8 xf0 = *(const short8*)(xrow + m * 64 + koff);
    short8 xf1 = *(const short8*)(xrow + m * 64 + 32 + koff);
    f32x4 acc[8];
#pragma unroll
    for (int nf = 0; nf < 8; ++nf) acc[nf] = (f32x4){0.f, 0.f, 0.f, 0.f};
#pragma unroll
    for (int nf = 0; nf < 8; ++nf) {
        short8 vf0 = *(const short8*)(Vpc + ((nf * 2 + 0) * 64 + l) * 8);
        short8 vf1 = *(const short8*)(Vpc + ((nf * 2 + 1) * 64 + l) * 8);
        acc[nf] = MFMA(vf0, xf0, acc[nf]);
        acc[nf] = MFMA(vf1, xf1, acc[nf]);
    }
#pragma unroll
    for (int nf = 0; nf < 8; ++nf) {
        short4v t;
        t[0] = bfbits(acc[nf][0]); t[1] = bfbits(acc[nf][1]);
        t[2] = bfbits(acc[nf][2]); t[3] = bfbits(acc[nf][3]);
        *(short4v*)(&Sl[m * 136 + nf * 16 + (l >> 4) * 4]) = t;
    }
    asm volatile("" ::: "memory");     // compiler fence; DS pipe is in-order/wave

    // ---- phase 2a: local scan (lane = mode n, own wave's 16 chunks) ----
    float2 lt = lamT[c * NN + l];
    float lpr[16], lpi[16];
    float sr = 0.f, si = 0.f;
#pragma unroll
    for (int k = 0; k < 16; ++k) {
        lpr[k] = sr; lpi[k] = si;
        uint pk = *(const uint*)(&Sl[(16 * w + k) * 136 + 2 * l]);
        float pr = __uint_as_float(pk << 16);
        float pi = __uint_as_float(pk & 0xffff0000u);
        float nr = fmaf(lt.x, sr, fmaf(-lt.y, si, pr));
        si = fmaf(lt.x, si, fmaf(lt.y, sr, pi));
        sr = nr;
    }
    cbuf[w * 132 + 2 * l]     = sr;    // wave total T_w
    cbuf[w * 132 + 2 * l + 1] = si;
    __syncthreads();                   // the ONLY barrier

    // ---- phase 2b: carry combine, write Sprev (bf16) over own P rows ----
    float ar = lt.x, ai = lt.y;        // -> lamT^16 by squaring
#pragma unroll
    for (int s = 0; s < 4; ++s) {
        float na = ar * ar - ai * ai; ai = 2.f * ar * ai; ar = na;
    }
    float a2r = ar * ar - ai * ai, a2i = 2.f * ar * ai;   // lamT^32
    float cr = 0.f, ci = 0.f;
    if (w >= 1) {
        float t0r = cbuf[2 * l], t0i = cbuf[2 * l + 1];
        if (w == 1) { cr = t0r; ci = t0i; }
        else if (w == 2) {
            cr = ar * t0r - ai * t0i + cbuf[132 + 2 * l];
            ci = ar * t0i + ai * t0r + cbuf[132 + 2 * l + 1];
        } else {
            float t1r = cbuf[132 + 2 * l], t1i = cbuf[132 + 2 * l + 1];
            cr = a2r * t0r - a2i * t0i + ar * t1r - ai * t1i + cbuf[264 + 2 * l];
            ci = a2r * t0i + a2i * t0r + ar * t1i + ai * t1r + cbuf[264 + 2 * l + 1];
        }
    }
#pragma unroll
    for (int k = 0; k < 16; ++k) {
        union { short2 s2; uint uu; } pk;
        pk.s2.x = bfbits(lpr[k] + cr);
        pk.s2.y = bfbits(lpi[k] + ci);
        *(uint*)(&Sl[(16 * w + k) * 136 + 2 * l]) = pk.uu;
        float ncr = cr * lt.x - ci * lt.y;
        ci = cr * lt.y + ci * lt.x;
        cr = ncr;
    }
    asm volatile("" ::: "memory");

    // ---- phase 3: v[i][m] = sum_k W2[k][i] * [x|Sprev][m][k]  (K=192) ----
    f32x4 o[4];
#pragma unroll
    for (int nf = 0; nf < 4; ++nf) o[nf] = (f32x4){0.f, 0.f, 0.f, 0.f};
#pragma unroll
    for (int ks = 0; ks < 6; ++ks) {
        short8 xf;
        if (ks == 0)      xf = xf0;
        else if (ks == 1) xf = xf1;
        else              xf = *(const short8*)(&Sl[m * 136 + (ks - 2) * 32 + koff]);
#pragma unroll
        for (int nf = 0; nf < 4; ++nf) {
            short8 wf = *(const short8*)(W2c + ((nf * 6 + ks) * 64 + l) * 8);
            o[nf] = MFMA(wf, xf, o[nf]);
        }
    }
    bf16* vrow = v + ((size_t)(b * CC + c)) * LL;
#pragma unroll
    for (int nf = 0; nf < 4; ++nf) {
        short4v t;
        t[0] = bfbits(o[nf][0]); t[1] = bfbits(o[nf][1]);
        t[2] = bfbits(o[nf][2]); t[3] = bfbits(o[nf][3]);
        *(short4v*)(vrow + m * 64 + nf * 16 + (l >> 4) * 4) = t;
    }
}

// ---------------------------------------------------------------------------
// LayerNorm over C (bf16 in/out, bf16-bits tile -> 8 blocks/CU);
// final layer fuses head projection (fp32 out).
// ---------------------------------------------------------------------------
__global__ __launch_bounds__(256, 8) void ln_kernel(
    const bf16* __restrict__ v, bf16* __restrict__ outx,
    const float* __restrict__ w, const float* __restrict__ bta,
    const float* __restrict__ headw, const float* __restrict__ headb,
    float* __restrict__ fout, int isfinal)
{
    __shared__ short tile[CC][66];
    __shared__ float r1[4][64];
    __shared__ float r2[4][64];
    __shared__ float mrs[2][64];
    int b    = blockIdx.y;
    int l0   = blockIdx.x * 64;
    int lane = threadIdx.x & 63;
    int cg   = threadIdx.x >> 6;
    const short* vv = (const short*)v;
    float sum = 0.0f, sq = 0.0f;
#pragma unroll
    for (int ci = 0; ci < 32; ++ci) {
        int c = cg * 32 + ci;
        short bits = vv[((size_t)b * CC + c) * LL + l0 + lane];
        float val = frombits(bits);
        tile[c][lane] = bits;
        sum += val;
        sq = fmaf(val, val, sq);
    }
    r1[cg][lane] = sum;
    r2[cg][lane] = sq;
    __syncthreads();
    if (cg == 0) {
        float s = r1[0][lane] + r1[1][lane] + r1[2][lane] + r1[3][lane];
        float q = r2[0][lane] + r2[1][lane] + r2[2][lane] + r2[3][lane];
        float mean = s * (1.0f / CC);
        float var  = q * (1.0f / CC) - mean * mean;
        mrs[0][lane] = mean;
        mrs[1][lane] = rsqrtf(var + EPSV);
    }
    __syncthreads();
    float mean = mrs[0][lane], rstd = mrs[1][lane];
    if (!isfinal) {
#pragma unroll
        for (int ci = 0; ci < 32; ++ci) {
            int c = cg * 32 + ci;
            float o = (frombits(tile[c][lane]) - mean) * rstd * w[c] + bta[c];
            outx[((size_t)b * CC + c) * LL + l0 + lane] = tobf(o);
        }
    } else {
        float h = 0.0f;
#pragma unroll
        for (int ci = 0; ci < 32; ++ci) {
            int c = cg * 32 + ci;
            float o = (frombits(tile[c][lane]) - mean) * rstd * w[c] + bta[c];
            h = fmaf(o, headw[c], h);
        }
        __syncthreads();
        r1[cg][lane] = h;
        __syncthreads();
        if (cg == 0)
            fout[(size_t)b * LL + l0 + lane] =
                r1[0][lane] + r1[1][lane] + r1[2][lane] + r1[3][lane] + headb[0];
    }
}

// ---------------------------------------------------------------------------
extern "C" void kernel_launch(void* const* d_in, const int* in_sizes, int n_in,
                              void* d_out, int out_size, void* d_ws, size_t ws_size,
                              hipStream_t stream)
{
    const float* x      = (const float*)d_in[0];
    const float* log_dt = (const float*)d_in[1];
    const float* A_real = (const float*)d_in[2];
    const float* A_imag = (const float*)d_in[3];
    const float* C_re   = (const float*)d_in[4];
    const float* C_im   = (const float*)d_in[5];
    const float* Dskip  = (const float*)d_in[6];
    const float* norm_w = (const float*)d_in[7];
    const float* norm_b = (const float*)d_in[8];
    const float* head_w = (const float*)d_in[9];
    const float* head_b = (const float*)d_in[10];
    float* out = (float*)d_out;

    const size_t DCN = (size_t)DEPTH_ * CC * NN;
    const size_t BCL = (size_t)BB * CC * LL;

    float2* lam  = (float2*)d_ws;
    float2* dta  = lam + DCN;
    float2* cb2  = dta + DCN;
    float2* lamT = cb2 + DCN;
    float*  Kloc = (float*)(lamT + DCN);
    bf16*   u    = (bf16*)(Kloc + (size_t)DEPTH_ * CC * 64);
    bf16*   v    = u + BCL;
    bf16*   Vp   = v + BCL;
    bf16*   W2p  = Vp + (size_t)DEPTH_ * CC * 8192;

    p0_kernel<<<dim3(CC, DEPTH_), 64, 0, stream>>>(
        log_dt, A_real, A_imag, C_re, C_im, lam, dta, cb2, lamT);
    p1_kernel<<<dim3(CC, DEPTH_), 64, 0, stream>>>(cb2, lam, Kloc);
    p2v_kernel<<<(DEPTH_ * CC * 8192) / 256, 256, 0, stream>>>(dta, Vp);
    p2w_kernel<<<(DEPTH_ * CC * 12288) / 256, 256, 0, stream>>>(
        dta, cb2, Kloc, Dskip, W2p);
    transpose_kernel<<<dim3(CC / 64, LL / 64, BB), 256, 0, stream>>>(x, u);

    for (int d = 0; d < DEPTH_; ++d) {
        ks_kernel<<<dim3(BB, CC), 256, 0, stream>>>(
            u, v, Vp + (size_t)d * CC * 8192, W2p + (size_t)d * CC * 12288,
            lamT + (size_t)d * CC * NN);
        ln_kernel<<<dim3(LL / 64, BB), 256, 0, stream>>>(
            v, u, norm_w + d * CC, norm_b + d * CC,
            head_w, head_b, out, (d == DEPTH_ - 1) ? 1 : 0);
    }
}

// Round 5
// 244.459 us; speedup vs baseline: 1.4228x; 1.4228x over previous
//
#include <hip/hip_runtime.h>
#include <hip/hip_bf16.h>

// S4D regressor, chunked-scan MFMA formulation.
// R5: 8 blocks/CU WITHOUT spills — prefix state lives in LDS (RMW carry fix),
// phase-1 GEMM split into two halves to cap acc pressure; ln reverted to the
// R3 (f32-tile, uncapped) version that ran at its memory floor.
// B=32, L=4096, C=128, N=64, DEPTH=4, OUT=1.

#define BB     32
#define LL     4096
#define CC     128
#define NN     64
#define DEPTH_ 4
#define EPSV   1e-5f

typedef __attribute__((ext_vector_type(8))) short short8;
typedef __attribute__((ext_vector_type(4))) short short4v;
typedef __attribute__((ext_vector_type(4))) float f32x4;
typedef __hip_bfloat16 bf16;

#define MFMA(a, b, c) __builtin_amdgcn_mfma_f32_16x16x32_bf16(a, b, c, 0, 0, 0)

__device__ __forceinline__ bf16 tobf(float x) { return __float2bfloat16(x); }
__device__ __forceinline__ short bfbits(float x) {
    union { bf16 b; short s; } u; u.b = __float2bfloat16(x); return u.s;
}
__device__ __forceinline__ float frombits(short s) {
    return __uint_as_float(((uint)(ushort)s) << 16);
}

// ---------------------------------------------------------------------------
// P0: per (d,c,n): lam=exp(dt*A), dta=dt*A, cb2=2*C*(lam-1)/A, lamT=lam^64
// ---------------------------------------------------------------------------
__global__ __launch_bounds__(64) void p0_kernel(
    const float* __restrict__ log_dt, const float* __restrict__ A_real,
    const float* __restrict__ A_imag, const float* __restrict__ C_re,
    const float* __restrict__ C_im, float2* __restrict__ lam,
    float2* __restrict__ dta, float2* __restrict__ cb2,
    float2* __restrict__ lamT)
{
    int d = blockIdx.y, c = blockIdx.x, n = threadIdx.x;
    int idx = (d * CC + c) * NN + n;
    float dt  = expf(log_dt[d * CC + c]);
    float Ar  = -expf(A_real[idx]);
    float Ai  = A_imag[idx];
    float dtr = dt * Ar, dti = dt * Ai;
    float e   = expf(dtr);
    float lr  = e * cosf(dti), li = e * sinf(dti);
    float m    = Ar * Ar + Ai * Ai;
    float inv  = 1.0f / m;
    float numr = lr - 1.0f, numi = li;
    float br   = (numr * Ar + numi * Ai) * inv;
    float bi   = (numi * Ar - numr * Ai) * inv;
    float cre  = C_re[idx], cim = C_im[idx];
    lam[idx]  = make_float2(lr, li);
    dta[idx]  = make_float2(dtr, dti);
    cb2[idx]  = make_float2(2.0f * (cre * br - cim * bi),
                            2.0f * (cre * bi + cim * br));
    float eT = expf(64.0f * dtr);
    lamT[idx] = make_float2(eT * cosf(64.0f * dti), eT * sinf(64.0f * dti));
}

// ---------------------------------------------------------------------------
// P1: Kloc[d][c][delta] = Re sum_n cb2_n lam_n^delta   (delta = 0..63)
// ---------------------------------------------------------------------------
__global__ __launch_bounds__(64) void p1_kernel(
    const float2* __restrict__ cb2, const float2* __restrict__ lam,
    float* __restrict__ Kloc)
{
    __shared__ float st[64 * 65];
    int d = blockIdx.y, c = blockIdx.x, n = threadIdx.x;
    float2 p = cb2[(d * CC + c) * NN + n];
    float2 l = lam[(d * CC + c) * NN + n];
    for (int t = 0; t < 64; ++t) {
        st[t * 65 + n] = p.x;
        float nr = p.x * l.x - p.y * l.y;
        p.y = p.x * l.y + p.y * l.x;
        p.x = nr;
    }
    __syncthreads();
    float s = 0.0f;
#pragma unroll 16
    for (int j = 0; j < 64; ++j) s += st[n * 65 + j];
    Kloc[(d * CC + c) * 64 + n] = s;
}

// ---------------------------------------------------------------------------
// P2V: Vp packed [d][c][nf=8][ks=2][lane=64][e=8]: B[k][q]=Re/Im(lam_n^{63-k})
// ---------------------------------------------------------------------------
__global__ __launch_bounds__(256) void p2v_kernel(
    const float2* __restrict__ dta, bf16* __restrict__ Vp)
{
    int t = blockIdx.x * 256 + threadIdx.x;
    int e = t & 7, l = (t >> 3) & 63, ks = (t >> 9) & 1;
    int nf = (t >> 10) & 7, c = (t >> 13) & 127, d = t >> 20;
    int q = nf * 16 + (l & 15);
    int k = ks * 32 + (l >> 4) * 8 + e;
    int n = q >> 1;
    float2 a = dta[(d * CC + c) * NN + n];
    float p  = (float)(63 - k);
    float mag = expf(p * a.x);
    float ang = p * a.y;
    float val = (q & 1) ? mag * sinf(ang) : mag * cosf(ang);
    Vp[t] = tobf(val);
}

// ---------------------------------------------------------------------------
// P2W: W2p packed [d][c][nf=4][ks=6][lane=64][e=8]
// ---------------------------------------------------------------------------
__global__ __launch_bounds__(256) void p2w_kernel(
    const float2* __restrict__ dta, const float2* __restrict__ cb2,
    const float* __restrict__ Kloc, const float* __restrict__ Dskip,
    bf16* __restrict__ W2p)
{
    int t = blockIdx.x * 256 + threadIdx.x;
    int e = t & 7, l = (t >> 3) & 63;
    int r = t >> 9;
    int ks = r % 6; r /= 6;
    int nf = r & 3; r >>= 2;
    int c  = r & 127;
    int d  = r >> 7;
    int i = nf * 16 + (l & 15);
    int k = ks * 32 + (l >> 4) * 8 + e;
    float val;
    if (k < 64) {
        val = (k <= i) ? Kloc[(d * CC + c) * 64 + (i - k)] : 0.0f;
        if (k == i) val += Dskip[d * CC + c] + 1.0f;
    } else {
        int q = k - 64, n = q >> 1;
        float2 a  = dta[(d * CC + c) * NN + n];
        float2 cb = cb2[(d * CC + c) * NN + n];
        float p   = (float)(i + 1);
        float mag = expf(p * a.x);
        float ang = p * a.y;
        float re = mag * cosf(ang), im = mag * sinf(ang);
        float wre = cb.x * re - cb.y * im;
        float wim = cb.x * im + cb.y * re;
        val = (q & 1) ? -wim : wre;
    }
    W2p[t] = tobf(val);
}

// ---------------------------------------------------------------------------
// x [B,L,C] fp32 -> xt [B][C][L] bf16
// ---------------------------------------------------------------------------
__global__ __launch_bounds__(256) void transpose_kernel(
    const float* __restrict__ x, bf16* __restrict__ xt)
{
    __shared__ float t[64][65];
    int ct = blockIdx.x, lt = blockIdx.y, b = blockIdx.z;
    int tx = threadIdx.x & 63, ty = threadIdx.x >> 6;
    const size_t xbase = ((size_t)b * LL + (size_t)lt * 64) * CC + (size_t)ct * 64;
#pragma unroll
    for (int i = 0; i < 16; ++i)
        t[ty + 4 * i][tx] = x[xbase + (size_t)(ty + 4 * i) * CC + tx];
    __syncthreads();
    const size_t obase = ((size_t)b * CC + (size_t)ct * 64) * LL + (size_t)lt * 64;
#pragma unroll
    for (int i = 0; i < 16; ++i)
        xt[obase + (size_t)(ty + 4 * i) * LL + tx] = tobf(t[tx][ty + 4 * i]);
}

// ---------------------------------------------------------------------------
// KS: fused per-(b,c) layer kernel, 4 waves, per-wave phase independence.
// bf16 LDS state; prefix values kept in LDS (not registers); carry applied
// via per-wave RMW pass (wave 0 skips). One barrier total.
// ---------------------------------------------------------------------------
__global__ __launch_bounds__(256, 8) void ks_kernel(
    const bf16* __restrict__ u, bf16* __restrict__ v,
    const bf16* __restrict__ Vp, const bf16* __restrict__ W2p,
    const float2* __restrict__ lamT)
{
    int b = blockIdx.x, c = blockIdx.y;
    int w = threadIdx.x >> 6, l = threadIdx.x & 63;
    const bf16* xrow = u + ((size_t)(b * CC + c)) * LL;
    const bf16* Vpc  = Vp  + (size_t)c * 8192;
    const bf16* W2c  = W2p + (size_t)c * 12288;

    __shared__ short Sl[64 * 136];     // bf16 bits: P_k, then Sprev (17.4 KB)
    __shared__ float cbuf[4 * 132];    // carry exchange (2.1 KB)

    const int m    = 16 * w + (l & 15);    // this lane's chunk (MFMA B-col)
    const int koff = (l >> 4) * 8;

    short8 xf0 = *(const short8*)(xrow + m * 64 + koff);
    short8 xf1 = *(const short8*)(xrow + m * 64 + 32 + koff);

    // ---- phase 1: P[m][q] = sum_k Vp[k][q] * x[m][k]  (two 4-nf halves) ----
#pragma unroll
    for (int h = 0; h < 2; ++h) {
        f32x4 acc[4];
#pragma unroll
        for (int j = 0; j < 4; ++j) acc[j] = (f32x4){0.f, 0.f, 0.f, 0.f};
#pragma unroll
        for (int j = 0; j < 4; ++j) {
            int nf = h * 4 + j;
            short8 vf0 = *(const short8*)(Vpc + ((nf * 2 + 0) * 64 + l) * 8);
            short8 vf1 = *(const short8*)(Vpc + ((nf * 2 + 1) * 64 + l) * 8);
            acc[j] = MFMA(vf0, xf0, acc[j]);
            acc[j] = MFMA(vf1, xf1, acc[j]);
        }
#pragma unroll
        for (int j = 0; j < 4; ++j) {
            int nf = h * 4 + j;
            short4v t;
            t[0] = bfbits(acc[j][0]); t[1] = bfbits(acc[j][1]);
            t[2] = bfbits(acc[j][2]); t[3] = bfbits(acc[j][3]);
            *(short4v*)(&Sl[m * 136 + nf * 16 + (l >> 4) * 4]) = t;
        }
    }
    asm volatile("" ::: "memory");     // same-wave DS ordering is in-order

    // ---- phase 2a: local scan; prefix (pre-chunk state) written to LDS ----
    float2 lt = lamT[c * NN + l];
    float sr = 0.f, si = 0.f;
#pragma unroll
    for (int k = 0; k < 16; ++k) {
        uint pk = *(const uint*)(&Sl[(16 * w + k) * 136 + 2 * l]);
        union { short2 s2; uint uu; } lpk;
        lpk.s2.x = bfbits(sr); lpk.s2.y = bfbits(si);
        *(uint*)(&Sl[(16 * w + k) * 136 + 2 * l]) = lpk.uu;   // lp[k] over P[k]
        float pr = __uint_as_float(pk << 16);
        float pi = __uint_as_float(pk & 0xffff0000u);
        float nr = fmaf(lt.x, sr, fmaf(-lt.y, si, pr));
        si = fmaf(lt.x, si, fmaf(lt.y, sr, pi));
        sr = nr;
    }
    cbuf[w * 132 + 2 * l]     = sr;    // wave total T_w
    cbuf[w * 132 + 2 * l + 1] = si;
    __syncthreads();                   // the ONLY barrier

    // ---- phase 2b: carry combine; RMW own rows (wave 0 skips: carry=0) ----
    if (w >= 1) {
        float ar = lt.x, ai = lt.y;    // -> lamT^16 by squaring
#pragma unroll
        for (int s = 0; s < 4; ++s) {
            float na = ar * ar - ai * ai; ai = 2.f * ar * ai; ar = na;
        }
        float cr, ci;
        float t0r = cbuf[2 * l], t0i = cbuf[2 * l + 1];
        if (w == 1) { cr = t0r; ci = t0i; }
        else if (w == 2) {
            cr = ar * t0r - ai * t0i + cbuf[132 + 2 * l];
            ci = ar * t0i + ai * t0r + cbuf[132 + 2 * l + 1];
        } else {
            float a2r = ar * ar - ai * ai, a2i = 2.f * ar * ai;  // lamT^32
            float t1r = cbuf[132 + 2 * l], t1i = cbuf[132 + 2 * l + 1];
            cr = a2r * t0r - a2i * t0i + ar * t1r - ai * t1i + cbuf[264 + 2 * l];
            ci = a2r * t0i + a2i * t0r + ar * t1i + ai * t1r + cbuf[264 + 2 * l + 1];
        }
#pragma unroll
        for (int k = 0; k < 16; ++k) {
            uint pk = *(const uint*)(&Sl[(16 * w + k) * 136 + 2 * l]);
            union { short2 s2; uint uu; } o;
            o.s2.x = bfbits(frombits((short)(pk & 0xffff)) + cr);
            o.s2.y = bfbits(frombits((short)(pk >> 16)) + ci);
            *(uint*)(&Sl[(16 * w + k) * 136 + 2 * l]) = o.uu;
            float ncr = cr * lt.x - ci * lt.y;
            ci = cr * lt.y + ci * lt.x;
            cr = ncr;
        }
    }
    asm volatile("" ::: "memory");

    // ---- phase 3: v[i][m] = sum_k W2[k][i] * [x|Sprev][m][k]  (K=192) ----
    f32x4 o[4];
#pragma unroll
    for (int nf = 0; nf < 4; ++nf) o[nf] = (f32x4){0.f, 0.f, 0.f, 0.f};
#pragma unroll
    for (int ks = 0; ks < 6; ++ks) {
        short8 xf;
        if (ks == 0)      xf = xf0;
        else if (ks == 1) xf = xf1;
        else              xf = *(const short8*)(&Sl[m * 136 + (ks - 2) * 32 + koff]);
#pragma unroll
        for (int nf = 0; nf < 4; ++nf) {
            short8 wf = *(const short8*)(W2c + ((nf * 6 + ks) * 64 + l) * 8);
            o[nf] = MFMA(wf, xf, o[nf]);
        }
    }
    bf16* vrow = v + ((size_t)(b * CC + c)) * LL;
#pragma unroll
    for (int nf = 0; nf < 4; ++nf) {
        short4v t;
        t[0] = bfbits(o[nf][0]); t[1] = bfbits(o[nf][1]);
        t[2] = bfbits(o[nf][2]); t[3] = bfbits(o[nf][3]);
        *(short4v*)(vrow + m * 64 + nf * 16 + (l >> 4) * 4) = t;
    }
}

// ---------------------------------------------------------------------------
// LayerNorm over C (bf16 in/out); final layer fuses head projection (fp32).
// R3 form: f32 tile, no launch-bounds cap (was at its memory floor).
// ---------------------------------------------------------------------------
__global__ __launch_bounds__(256) void ln_kernel(
    const bf16* __restrict__ v, bf16* __restrict__ outx,
    const float* __restrict__ w, const float* __restrict__ bta,
    const float* __restrict__ headw, const float* __restrict__ headb,
    float* __restrict__ fout, int isfinal)
{
    __shared__ float tile[CC][65];
    __shared__ float r1[4][64];
    __shared__ float r2[4][64];
    __shared__ float mrs[2][64];
    int b    = blockIdx.y;
    int l0   = blockIdx.x * 64;
    int lane = threadIdx.x & 63;
    int cg   = threadIdx.x >> 6;
    float sum = 0.0f, sq = 0.0f;
#pragma unroll
    for (int ci = 0; ci < 32; ++ci) {
        int c = cg * 32 + ci;
        float val = __bfloat162float(v[((size_t)b * CC + c) * LL + l0 + lane]);
        tile[c][lane] = val;
        sum += val;
        sq = fmaf(val, val, sq);
    }
    r1[cg][lane] = sum;
    r2[cg][lane] = sq;
    __syncthreads();
    if (cg == 0) {
        float s = r1[0][lane] + r1[1][lane] + r1[2][lane] + r1[3][lane];
        float q = r2[0][lane] + r2[1][lane] + r2[2][lane] + r2[3][lane];
        float mean = s * (1.0f / CC);
        float var  = q * (1.0f / CC) - mean * mean;
        mrs[0][lane] = mean;
        mrs[1][lane] = rsqrtf(var + EPSV);
    }
    __syncthreads();
    float mean = mrs[0][lane], rstd = mrs[1][lane];
    if (!isfinal) {
#pragma unroll
        for (int ci = 0; ci < 32; ++ci) {
            int c = cg * 32 + ci;
            float o = (tile[c][lane] - mean) * rstd * w[c] + bta[c];
            outx[((size_t)b * CC + c) * LL + l0 + lane] = tobf(o);
        }
    } else {
        float h = 0.0f;
#pragma unroll
        for (int ci = 0; ci < 32; ++ci) {
            int c = cg * 32 + ci;
            float o = (tile[c][lane] - mean) * rstd * w[c] + bta[c];
            h = fmaf(o, headw[c], h);
        }
        __syncthreads();
        r1[cg][lane] = h;
        __syncthreads();
        if (cg == 0)
            fout[(size_t)b * LL + l0 + lane] =
                r1[0][lane] + r1[1][lane] + r1[2][lane] + r1[3][lane] + headb[0];
    }
}

// ---------------------------------------------------------------------------
extern "C" void kernel_launch(void* const* d_in, const int* in_sizes, int n_in,
                              void* d_out, int out_size, void* d_ws, size_t ws_size,
                              hipStream_t stream)
{
    const float* x      = (const float*)d_in[0];
    const float* log_dt = (const float*)d_in[1];
    const float* A_real = (const float*)d_in[2];
    const float* A_imag = (const float*)d_in[3];
    const float* C_re   = (const float*)d_in[4];
    const float* C_im   = (const float*)d_in[5];
    const float* Dskip  = (const float*)d_in[6];
    const float* norm_w = (const float*)d_in[7];
    const float* norm_b = (const float*)d_in[8];
    const float* head_w = (const float*)d_in[9];
    const float* head_b = (const float*)d_in[10];
    float* out = (float*)d_out;

    const size_t DCN = (size_t)DEPTH_ * CC * NN;
    const size_t BCL = (size_t)BB * CC * LL;

    float2* lam  = (float2*)d_ws;
    float2* dta  = lam + DCN;
    float2* cb2  = dta + DCN;
    float2* lamT = cb2 + DCN;
    float*  Kloc = (float*)(lamT + DCN);
    bf16*   u    = (bf16*)(Kloc + (size_t)DEPTH_ * CC * 64);
    bf16*   v    = u + BCL;
    bf16*   Vp   = v + BCL;
    bf16*   W2p  = Vp + (size_t)DEPTH_ * CC * 8192;

    p0_kernel<<<dim3(CC, DEPTH_), 64, 0, stream>>>(
        log_dt, A_real, A_imag, C_re, C_im, lam, dta, cb2, lamT);
    p1_kernel<<<dim3(CC, DEPTH_), 64, 0, stream>>>(cb2, lam, Kloc);
    p2v_kernel<<<(DEPTH_ * CC * 8192) / 256, 256, 0, stream>>>(dta, Vp);
    p2w_kernel<<<(DEPTH_ * CC * 12288) / 256, 256, 0, stream>>>(
        dta, cb2, Kloc, Dskip, W2p);
    transpose_kernel<<<dim3(CC / 64, LL / 64, BB), 256, 0, stream>>>(x, u);

    for (int d = 0; d < DEPTH_; ++d) {
        ks_kernel<<<dim3(BB, CC), 256, 0, stream>>>(
            u, v, Vp + (size_t)d * CC * 8192, W2p + (size_t)d * CC * 12288,
            lamT + (size_t)d * CC * NN);
        ln_kernel<<<dim3(LL / 64, BB), 256, 0, stream>>>(
            v, u, norm_w + d * CC, norm_b + d * CC,
            head_w, head_b, out, (d == DEPTH_ - 1) ? 1 : 0);
    }
}

// Round 6
// 242.841 us; speedup vs baseline: 1.4322x; 1.0067x over previous
//
#include <hip/hip_runtime.h>
#include <hip/hip_bf16.h>

// S4D regressor, chunked-scan MFMA formulation.
// R6: prefix kept as 16 PACKED bf16x2 uints in registers (fits 64-VGPR/8-wave
// budget, unlike R4's 32 floats); phase2b is reg->LDS only (no RMW round-trip).
// -32 LDS ops and ~200 VALU cycles per wave vs R5; one barrier total.
// B=32, L=4096, C=128, N=64, DEPTH=4, OUT=1.

#define BB     32
#define LL     4096
#define CC     128
#define NN     64
#define DEPTH_ 4
#define EPSV   1e-5f

typedef __attribute__((ext_vector_type(8))) short short8;
typedef __attribute__((ext_vector_type(4))) short short4v;
typedef __attribute__((ext_vector_type(4))) float f32x4;
typedef __hip_bfloat16 bf16;

#define MFMA(a, b, c) __builtin_amdgcn_mfma_f32_16x16x32_bf16(a, b, c, 0, 0, 0)

__device__ __forceinline__ bf16 tobf(float x) { return __float2bfloat16(x); }
__device__ __forceinline__ short bfbits(float x) {
    union { bf16 b; short s; } u; u.b = __float2bfloat16(x); return u.s;
}
__device__ __forceinline__ float frombits(short s) {
    return __uint_as_float(((uint)(ushort)s) << 16);
}

// ---------------------------------------------------------------------------
// P0: per (d,c,n): lam=exp(dt*A), dta=dt*A, cb2=2*C*(lam-1)/A, lamT=lam^64
// ---------------------------------------------------------------------------
__global__ __launch_bounds__(64) void p0_kernel(
    const float* __restrict__ log_dt, const float* __restrict__ A_real,
    const float* __restrict__ A_imag, const float* __restrict__ C_re,
    const float* __restrict__ C_im, float2* __restrict__ lam,
    float2* __restrict__ dta, float2* __restrict__ cb2,
    float2* __restrict__ lamT)
{
    int d = blockIdx.y, c = blockIdx.x, n = threadIdx.x;
    int idx = (d * CC + c) * NN + n;
    float dt  = expf(log_dt[d * CC + c]);
    float Ar  = -expf(A_real[idx]);
    float Ai  = A_imag[idx];
    float dtr = dt * Ar, dti = dt * Ai;
    float e   = expf(dtr);
    float lr  = e * cosf(dti), li = e * sinf(dti);
    float m    = Ar * Ar + Ai * Ai;
    float inv  = 1.0f / m;
    float numr = lr - 1.0f, numi = li;
    float br   = (numr * Ar + numi * Ai) * inv;
    float bi   = (numi * Ar - numr * Ai) * inv;
    float cre  = C_re[idx], cim = C_im[idx];
    lam[idx]  = make_float2(lr, li);
    dta[idx]  = make_float2(dtr, dti);
    cb2[idx]  = make_float2(2.0f * (cre * br - cim * bi),
                            2.0f * (cre * bi + cim * br));
    float eT = expf(64.0f * dtr);
    lamT[idx] = make_float2(eT * cosf(64.0f * dti), eT * sinf(64.0f * dti));
}

// ---------------------------------------------------------------------------
// P1: Kloc[d][c][delta] = Re sum_n cb2_n lam_n^delta   (delta = 0..63)
// ---------------------------------------------------------------------------
__global__ __launch_bounds__(64) void p1_kernel(
    const float2* __restrict__ cb2, const float2* __restrict__ lam,
    float* __restrict__ Kloc)
{
    __shared__ float st[64 * 65];
    int d = blockIdx.y, c = blockIdx.x, n = threadIdx.x;
    float2 p = cb2[(d * CC + c) * NN + n];
    float2 l = lam[(d * CC + c) * NN + n];
    for (int t = 0; t < 64; ++t) {
        st[t * 65 + n] = p.x;
        float nr = p.x * l.x - p.y * l.y;
        p.y = p.x * l.y + p.y * l.x;
        p.x = nr;
    }
    __syncthreads();
    float s = 0.0f;
#pragma unroll 16
    for (int j = 0; j < 64; ++j) s += st[n * 65 + j];
    Kloc[(d * CC + c) * 64 + n] = s;
}

// ---------------------------------------------------------------------------
// P2V: Vp packed [d][c][nf=8][ks=2][lane=64][e=8]: B[k][q]=Re/Im(lam_n^{63-k})
// ---------------------------------------------------------------------------
__global__ __launch_bounds__(256) void p2v_kernel(
    const float2* __restrict__ dta, bf16* __restrict__ Vp)
{
    int t = blockIdx.x * 256 + threadIdx.x;
    int e = t & 7, l = (t >> 3) & 63, ks = (t >> 9) & 1;
    int nf = (t >> 10) & 7, c = (t >> 13) & 127, d = t >> 20;
    int q = nf * 16 + (l & 15);
    int k = ks * 32 + (l >> 4) * 8 + e;
    int n = q >> 1;
    float2 a = dta[(d * CC + c) * NN + n];
    float p  = (float)(63 - k);
    float mag = expf(p * a.x);
    float ang = p * a.y;
    float val = (q & 1) ? mag * sinf(ang) : mag * cosf(ang);
    Vp[t] = tobf(val);
}

// ---------------------------------------------------------------------------
// P2W: W2p packed [d][c][nf=4][ks=6][lane=64][e=8]
// ---------------------------------------------------------------------------
__global__ __launch_bounds__(256) void p2w_kernel(
    const float2* __restrict__ dta, const float2* __restrict__ cb2,
    const float* __restrict__ Kloc, const float* __restrict__ Dskip,
    bf16* __restrict__ W2p)
{
    int t = blockIdx.x * 256 + threadIdx.x;
    int e = t & 7, l = (t >> 3) & 63;
    int r = t >> 9;
    int ks = r % 6; r /= 6;
    int nf = r & 3; r >>= 2;
    int c  = r & 127;
    int d  = r >> 7;
    int i = nf * 16 + (l & 15);
    int k = ks * 32 + (l >> 4) * 8 + e;
    float val;
    if (k < 64) {
        val = (k <= i) ? Kloc[(d * CC + c) * 64 + (i - k)] : 0.0f;
        if (k == i) val += Dskip[d * CC + c] + 1.0f;
    } else {
        int q = k - 64, n = q >> 1;
        float2 a  = dta[(d * CC + c) * NN + n];
        float2 cb = cb2[(d * CC + c) * NN + n];
        float p   = (float)(i + 1);
        float mag = expf(p * a.x);
        float ang = p * a.y;
        float re = mag * cosf(ang), im = mag * sinf(ang);
        float wre = cb.x * re - cb.y * im;
        float wim = cb.x * im + cb.y * re;
        val = (q & 1) ? -wim : wre;
    }
    W2p[t] = tobf(val);
}

// ---------------------------------------------------------------------------
// x [B,L,C] fp32 -> xt [B][C][L] bf16
// ---------------------------------------------------------------------------
__global__ __launch_bounds__(256) void transpose_kernel(
    const float* __restrict__ x, bf16* __restrict__ xt)
{
    __shared__ float t[64][65];
    int ct = blockIdx.x, lt = blockIdx.y, b = blockIdx.z;
    int tx = threadIdx.x & 63, ty = threadIdx.x >> 6;
    const size_t xbase = ((size_t)b * LL + (size_t)lt * 64) * CC + (size_t)ct * 64;
#pragma unroll
    for (int i = 0; i < 16; ++i)
        t[ty + 4 * i][tx] = x[xbase + (size_t)(ty + 4 * i) * CC + tx];
    __syncthreads();
    const size_t obase = ((size_t)b * CC + (size_t)ct * 64) * LL + (size_t)lt * 64;
#pragma unroll
    for (int i = 0; i < 16; ++i)
        xt[obase + (size_t)(ty + 4 * i) * LL + tx] = tobf(t[tx][ty + 4 * i]);
}

// ---------------------------------------------------------------------------
// KS: fused per-(b,c) layer kernel, 4 waves, per-wave phase independence.
// Prefix state in 16 packed-uint registers; phase2b is store-only. 1 barrier.
// ---------------------------------------------------------------------------
__global__ __launch_bounds__(256, 8) void ks_kernel(
    const bf16* __restrict__ u, bf16* __restrict__ v,
    const bf16* __restrict__ Vp, const bf16* __restrict__ W2p,
    const float2* __restrict__ lamT)
{
    int b = blockIdx.x, c = blockIdx.y;
    int w = threadIdx.x >> 6, l = threadIdx.x & 63;
    const bf16* xrow = u + ((size_t)(b * CC + c)) * LL;
    const bf16* Vpc  = Vp  + (size_t)c * 8192;
    const bf16* W2c  = W2p + (size_t)c * 12288;

    __shared__ short Sl[64 * 136];     // bf16 bits: P_k, then Sprev (17.4 KB)
    __shared__ float cbuf[4 * 132];    // carry exchange (2.1 KB)

    const int m    = 16 * w + (l & 15);    // this lane's chunk (MFMA B-col)
    const int koff = (l >> 4) * 8;

    short8 xf0 = *(const short8*)(xrow + m * 64 + koff);
    short8 xf1 = *(const short8*)(xrow + m * 64 + 32 + koff);

    // ---- phase 1: P[m][q] = sum_k Vp[k][q] * x[m][k]  (two 4-nf halves) ----
#pragma unroll
    for (int h = 0; h < 2; ++h) {
        f32x4 acc[4];
#pragma unroll
        for (int j = 0; j < 4; ++j) acc[j] = (f32x4){0.f, 0.f, 0.f, 0.f};
#pragma unroll
        for (int j = 0; j < 4; ++j) {
            int nf = h * 4 + j;
            short8 vf0 = *(const short8*)(Vpc + ((nf * 2 + 0) * 64 + l) * 8);
            short8 vf1 = *(const short8*)(Vpc + ((nf * 2 + 1) * 64 + l) * 8);
            acc[j] = MFMA(vf0, xf0, acc[j]);
            acc[j] = MFMA(vf1, xf1, acc[j]);
        }
#pragma unroll
        for (int j = 0; j < 4; ++j) {
            int nf = h * 4 + j;
            short4v t;
            t[0] = bfbits(acc[j][0]); t[1] = bfbits(acc[j][1]);
            t[2] = bfbits(acc[j][2]); t[3] = bfbits(acc[j][3]);
            *(short4v*)(&Sl[m * 136 + nf * 16 + (l >> 4) * 4]) = t;
        }
    }
    asm volatile("" ::: "memory");     // same-wave DS ordering is in-order

    // ---- phase 2a: local scan; prefix packed into registers ----
    float2 lt = lamT[c * NN + l];
    uint lp[16];
    float sr = 0.f, si = 0.f;
#pragma unroll
    for (int k = 0; k < 16; ++k) {
        uint pk = *(const uint*)(&Sl[(16 * w + k) * 136 + 2 * l]);
        union { short2 s2; uint uu; } lpk;
        lpk.s2.x = bfbits(sr); lpk.s2.y = bfbits(si);
        lp[k] = lpk.uu;                           // packed prefix (pre-chunk)
        float pr = __uint_as_float(pk << 16);
        float pi = __uint_as_float(pk & 0xffff0000u);
        float nr = fmaf(lt.x, sr, fmaf(-lt.y, si, pr));
        si = fmaf(lt.x, si, fmaf(lt.y, sr, pi));
        sr = nr;
    }
    cbuf[w * 132 + 2 * l]     = sr;    // wave total T_w
    cbuf[w * 132 + 2 * l + 1] = si;
    __syncthreads();                   // the ONLY barrier

    // ---- phase 2b: carry combine; write Sprev rows (store-only) ----
    if (w == 0) {
#pragma unroll
        for (int k = 0; k < 16; ++k)
            *(uint*)(&Sl[k * 136 + 2 * l]) = lp[k];    // carry = 0
    } else {
        float ar = lt.x, ai = lt.y;    // -> lamT^16 by squaring
#pragma unroll
        for (int s = 0; s < 4; ++s) {
            float na = ar * ar - ai * ai; ai = 2.f * ar * ai; ar = na;
        }
        float cr, ci;
        float t0r = cbuf[2 * l], t0i = cbuf[2 * l + 1];
        if (w == 1) { cr = t0r; ci = t0i; }
        else if (w == 2) {
            cr = ar * t0r - ai * t0i + cbuf[132 + 2 * l];
            ci = ar * t0i + ai * t0r + cbuf[132 + 2 * l + 1];
        } else {
            float a2r = ar * ar - ai * ai, a2i = 2.f * ar * ai;  // lamT^32
            float t1r = cbuf[132 + 2 * l], t1i = cbuf[132 + 2 * l + 1];
            cr = a2r * t0r - a2i * t0i + ar * t1r - ai * t1i + cbuf[264 + 2 * l];
            ci = a2r * t0i + a2i * t0r + ar * t1i + ai * t1r + cbuf[264 + 2 * l + 1];
        }
#pragma unroll
        for (int k = 0; k < 16; ++k) {
            float pr = __uint_as_float(lp[k] << 16) + cr;
            float pi = __uint_as_float(lp[k] & 0xffff0000u) + ci;
            union { short2 s2; uint uu; } o;
            o.s2.x = bfbits(pr); o.s2.y = bfbits(pi);
            *(uint*)(&Sl[(16 * w + k) * 136 + 2 * l]) = o.uu;
            float ncr = cr * lt.x - ci * lt.y;
            ci = cr * lt.y + ci * lt.x;
            cr = ncr;
        }
    }
    asm volatile("" ::: "memory");

    // ---- phase 3: v[i][m] = sum_k W2[k][i] * [x|Sprev][m][k]  (K=192) ----
    f32x4 o[4];
#pragma unroll
    for (int nf = 0; nf < 4; ++nf) o[nf] = (f32x4){0.f, 0.f, 0.f, 0.f};
#pragma unroll
    for (int ks = 0; ks < 6; ++ks) {
        short8 xf;
        if (ks == 0)      xf = xf0;
        else if (ks == 1) xf = xf1;
        else              xf = *(const short8*)(&Sl[m * 136 + (ks - 2) * 32 + koff]);
#pragma unroll
        for (int nf = 0; nf < 4; ++nf) {
            short8 wf = *(const short8*)(W2c + ((nf * 6 + ks) * 64 + l) * 8);
            o[nf] = MFMA(wf, xf, o[nf]);
        }
    }
    bf16* vrow = v + ((size_t)(b * CC + c)) * LL;
#pragma unroll
    for (int nf = 0; nf < 4; ++nf) {
        short4v t;
        t[0] = bfbits(o[nf][0]); t[1] = bfbits(o[nf][1]);
        t[2] = bfbits(o[nf][2]); t[3] = bfbits(o[nf][3]);
        *(short4v*)(vrow + m * 64 + nf * 16 + (l >> 4) * 4) = t;
    }
}

// ---------------------------------------------------------------------------
// LayerNorm over C (bf16 in/out); final layer fuses head projection (fp32).
// ---------------------------------------------------------------------------
__global__ __launch_bounds__(256) void ln_kernel(
    const bf16* __restrict__ v, bf16* __restrict__ outx,
    const float* __restrict__ w, const float* __restrict__ bta,
    const float* __restrict__ headw, const float* __restrict__ headb,
    float* __restrict__ fout, int isfinal)
{
    __shared__ float tile[CC][65];
    __shared__ float r1[4][64];
    __shared__ float r2[4][64];
    __shared__ float mrs[2][64];
    int b    = blockIdx.y;
    int l0   = blockIdx.x * 64;
    int lane = threadIdx.x & 63;
    int cg   = threadIdx.x >> 6;
    float sum = 0.0f, sq = 0.0f;
#pragma unroll
    for (int ci = 0; ci < 32; ++ci) {
        int c = cg * 32 + ci;
        float val = __bfloat162float(v[((size_t)b * CC + c) * LL + l0 + lane]);
        tile[c][lane] = val;
        sum += val;
        sq = fmaf(val, val, sq);
    }
    r1[cg][lane] = sum;
    r2[cg][lane] = sq;
    __syncthreads();
    if (cg == 0) {
        float s = r1[0][lane] + r1[1][lane] + r1[2][lane] + r1[3][lane];
        float q = r2[0][lane] + r2[1][lane] + r2[2][lane] + r2[3][lane];
        float mean = s * (1.0f / CC);
        float var  = q * (1.0f / CC) - mean * mean;
        mrs[0][lane] = mean;
        mrs[1][lane] = rsqrtf(var + EPSV);
    }
    __syncthreads();
    float mean = mrs[0][lane], rstd = mrs[1][lane];
    if (!isfinal) {
#pragma unroll
        for (int ci = 0; ci < 32; ++ci) {
            int c = cg * 32 + ci;
            float o = (tile[c][lane] - mean) * rstd * w[c] + bta[c];
            outx[((size_t)b * CC + c) * LL + l0 + lane] = tobf(o);
        }
    } else {
        float h = 0.0f;
#pragma unroll
        for (int ci = 0; ci < 32; ++ci) {
            int c = cg * 32 + ci;
            float o = (tile[c][lane] - mean) * rstd * w[c] + bta[c];
            h = fmaf(o, headw[c], h);
        }
        __syncthreads();
        r1[cg][lane] = h;
        __syncthreads();
        if (cg == 0)
            fout[(size_t)b * LL + l0 + lane] =
                r1[0][lane] + r1[1][lane] + r1[2][lane] + r1[3][lane] + headb[0];
    }
}

// ---------------------------------------------------------------------------
extern "C" void kernel_launch(void* const* d_in, const int* in_sizes, int n_in,
                              void* d_out, int out_size, void* d_ws, size_t ws_size,
                              hipStream_t stream)
{
    const float* x      = (const float*)d_in[0];
    const float* log_dt = (const float*)d_in[1];
    const float* A_real = (const float*)d_in[2];
    const float* A_imag = (const float*)d_in[3];
    const float* C_re   = (const float*)d_in[4];
    const float* C_im   = (const float*)d_in[5];
    const float* Dskip  = (const float*)d_in[6];
    const float* norm_w = (const float*)d_in[7];
    const float* norm_b = (const float*)d_in[8];
    const float* head_w = (const float*)d_in[9];
    const float* head_b = (const float*)d_in[10];
    float* out = (float*)d_out;

    const size_t DCN = (size_t)DEPTH_ * CC * NN;
    const size_t BCL = (size_t)BB * CC * LL;

    float2* lam  = (float2*)d_ws;
    float2* dta  = lam + DCN;
    float2* cb2  = dta + DCN;
    float2* lamT = cb2 + DCN;
    float*  Kloc = (float*)(lamT + DCN);
    bf16*   u    = (bf16*)(Kloc + (size_t)DEPTH_ * CC * 64);
    bf16*   v    = u + BCL;
    bf16*   Vp   = v + BCL;
    bf16*   W2p  = Vp + (size_t)DEPTH_ * CC * 8192;

    p0_kernel<<<dim3(CC, DEPTH_), 64, 0, stream>>>(
        log_dt, A_real, A_imag, C_re, C_im, lam, dta, cb2, lamT);
    p1_kernel<<<dim3(CC, DEPTH_), 64, 0, stream>>>(cb2, lam, Kloc);
    p2v_kernel<<<(DEPTH_ * CC * 8192) / 256, 256, 0, stream>>>(dta, Vp);
    p2w_kernel<<<(DEPTH_ * CC * 12288) / 256, 256, 0, stream>>>(
        dta, cb2, Kloc, Dskip, W2p);
    transpose_kernel<<<dim3(CC / 64, LL / 64, BB), 256, 0, stream>>>(x, u);

    for (int d = 0; d < DEPTH_; ++d) {
        ks_kernel<<<dim3(BB, CC), 256, 0, stream>>>(
            u, v, Vp + (size_t)d * CC * 8192, W2p + (size_t)d * CC * 12288,
            lamT + (size_t)d * CC * NN);
        ln_kernel<<<dim3(LL / 64, BB), 256, 0, stream>>>(
            v, u, norm_w + d * CC, norm_b + d * CC,
            head_w, head_b, out, (d == DEPTH_ - 1) ? 1 : 0);
    }
}

// Round 7
// 217.804 us; speedup vs baseline: 1.5969x; 1.1150x over previous
//
#include <hip/hip_runtime.h>
#include <hip/hip_bf16.h>

// S4D regressor, chunked-scan MFMA formulation.
// R7: ONE WAVE per (b,c) — zero barriers. Each wave processes 4 groups of 16
// chunks: {phase1 MFMA -> pack P to LDS -> 16-step private scan (P replaced
// in-place by Sprev) -> phase3 MFMA -> store}, double-buffered 2x4.4 KB LDS.
// No carry tree, no phase2b, no cross-wave traffic. 16 blocks/CU resident =
// every wave of work resident in a single round.
// B=32, L=4096, C=128, N=64, DEPTH=4, OUT=1.

#define BB     32
#define LL     4096
#define CC     128
#define NN     64
#define DEPTH_ 4
#define EPSV   1e-5f

typedef __attribute__((ext_vector_type(8))) short short8;
typedef __attribute__((ext_vector_type(4))) short short4v;
typedef __attribute__((ext_vector_type(4))) float f32x4;
typedef __hip_bfloat16 bf16;

#define MFMA(a, b, c) __builtin_amdgcn_mfma_f32_16x16x32_bf16(a, b, c, 0, 0, 0)

__device__ __forceinline__ bf16 tobf(float x) { return __float2bfloat16(x); }
__device__ __forceinline__ short bfbits(float x) {
    union { bf16 b; short s; } u; u.b = __float2bfloat16(x); return u.s;
}

// ---------------------------------------------------------------------------
// P0: per (d,c,n): lam=exp(dt*A), dta=dt*A, cb2=2*C*(lam-1)/A, lamT=lam^64
// ---------------------------------------------------------------------------
__global__ __launch_bounds__(64) void p0_kernel(
    const float* __restrict__ log_dt, const float* __restrict__ A_real,
    const float* __restrict__ A_imag, const float* __restrict__ C_re,
    const float* __restrict__ C_im, float2* __restrict__ lam,
    float2* __restrict__ dta, float2* __restrict__ cb2,
    float2* __restrict__ lamT)
{
    int d = blockIdx.y, c = blockIdx.x, n = threadIdx.x;
    int idx = (d * CC + c) * NN + n;
    float dt  = expf(log_dt[d * CC + c]);
    float Ar  = -expf(A_real[idx]);
    float Ai  = A_imag[idx];
    float dtr = dt * Ar, dti = dt * Ai;
    float e   = expf(dtr);
    float lr  = e * cosf(dti), li = e * sinf(dti);
    float m    = Ar * Ar + Ai * Ai;
    float inv  = 1.0f / m;
    float numr = lr - 1.0f, numi = li;
    float br   = (numr * Ar + numi * Ai) * inv;
    float bi   = (numi * Ar - numr * Ai) * inv;
    float cre  = C_re[idx], cim = C_im[idx];
    lam[idx]  = make_float2(lr, li);
    dta[idx]  = make_float2(dtr, dti);
    cb2[idx]  = make_float2(2.0f * (cre * br - cim * bi),
                            2.0f * (cre * bi + cim * br));
    float eT = expf(64.0f * dtr);
    lamT[idx] = make_float2(eT * cosf(64.0f * dti), eT * sinf(64.0f * dti));
}

// ---------------------------------------------------------------------------
// P1: Kloc[d][c][delta] = Re sum_n cb2_n lam_n^delta   (delta = 0..63)
// ---------------------------------------------------------------------------
__global__ __launch_bounds__(64) void p1_kernel(
    const float2* __restrict__ cb2, const float2* __restrict__ lam,
    float* __restrict__ Kloc)
{
    __shared__ float st[64 * 65];
    int d = blockIdx.y, c = blockIdx.x, n = threadIdx.x;
    float2 p = cb2[(d * CC + c) * NN + n];
    float2 l = lam[(d * CC + c) * NN + n];
    for (int t = 0; t < 64; ++t) {
        st[t * 65 + n] = p.x;
        float nr = p.x * l.x - p.y * l.y;
        p.y = p.x * l.y + p.y * l.x;
        p.x = nr;
    }
    __syncthreads();
    float s = 0.0f;
#pragma unroll 16
    for (int j = 0; j < 64; ++j) s += st[n * 65 + j];
    Kloc[(d * CC + c) * 64 + n] = s;
}

// ---------------------------------------------------------------------------
// P2V: Vp packed [d][c][nf=8][ks=2][lane=64][e=8]: B[k][q]=Re/Im(lam_n^{63-k})
// ---------------------------------------------------------------------------
__global__ __launch_bounds__(256) void p2v_kernel(
    const float2* __restrict__ dta, bf16* __restrict__ Vp)
{
    int t = blockIdx.x * 256 + threadIdx.x;
    int e = t & 7, l = (t >> 3) & 63, ks = (t >> 9) & 1;
    int nf = (t >> 10) & 7, c = (t >> 13) & 127, d = t >> 20;
    int q = nf * 16 + (l & 15);
    int k = ks * 32 + (l >> 4) * 8 + e;
    int n = q >> 1;
    float2 a = dta[(d * CC + c) * NN + n];
    float p  = (float)(63 - k);
    float mag = expf(p * a.x);
    float ang = p * a.y;
    float val = (q & 1) ? mag * sinf(ang) : mag * cosf(ang);
    Vp[t] = tobf(val);
}

// ---------------------------------------------------------------------------
// P2W: W2p packed [d][c][nf=4][ks=6][lane=64][e=8]
// ---------------------------------------------------------------------------
__global__ __launch_bounds__(256) void p2w_kernel(
    const float2* __restrict__ dta, const float2* __restrict__ cb2,
    const float* __restrict__ Kloc, const float* __restrict__ Dskip,
    bf16* __restrict__ W2p)
{
    int t = blockIdx.x * 256 + threadIdx.x;
    int e = t & 7, l = (t >> 3) & 63;
    int r = t >> 9;
    int ks = r % 6; r /= 6;
    int nf = r & 3; r >>= 2;
    int c  = r & 127;
    int d  = r >> 7;
    int i = nf * 16 + (l & 15);
    int k = ks * 32 + (l >> 4) * 8 + e;
    float val;
    if (k < 64) {
        val = (k <= i) ? Kloc[(d * CC + c) * 64 + (i - k)] : 0.0f;
        if (k == i) val += Dskip[d * CC + c] + 1.0f;
    } else {
        int q = k - 64, n = q >> 1;
        float2 a  = dta[(d * CC + c) * NN + n];
        float2 cb = cb2[(d * CC + c) * NN + n];
        float p   = (float)(i + 1);
        float mag = expf(p * a.x);
        float ang = p * a.y;
        float re = mag * cosf(ang), im = mag * sinf(ang);
        float wre = cb.x * re - cb.y * im;
        float wim = cb.x * im + cb.y * re;
        val = (q & 1) ? -wim : wre;
    }
    W2p[t] = tobf(val);
}

// ---------------------------------------------------------------------------
// x [B,L,C] fp32 -> xt [B][C][L] bf16
// ---------------------------------------------------------------------------
__global__ __launch_bounds__(256) void transpose_kernel(
    const float* __restrict__ x, bf16* __restrict__ xt)
{
    __shared__ float t[64][65];
    int ct = blockIdx.x, lt = blockIdx.y, b = blockIdx.z;
    int tx = threadIdx.x & 63, ty = threadIdx.x >> 6;
    const size_t xbase = ((size_t)b * LL + (size_t)lt * 64) * CC + (size_t)ct * 64;
#pragma unroll
    for (int i = 0; i < 16; ++i)
        t[ty + 4 * i][tx] = x[xbase + (size_t)(ty + 4 * i) * CC + tx];
    __syncthreads();
    const size_t obase = ((size_t)b * CC + (size_t)ct * 64) * LL + (size_t)lt * 64;
#pragma unroll
    for (int i = 0; i < 16; ++i)
        xt[obase + (size_t)(ty + 4 * i) * LL + tx] = tobf(t[tx][ty + 4 * i]);
}

// ---------------------------------------------------------------------------
// KS: ONE WAVE per (b,c). 4 sequential groups of 16 chunks; per group:
//   phase1: P[m][q] = sum_k Vp[k][q] x[m][k]   (16 MFMA, K=64)
//   scan  : 16 private steps, s_{k} = lamT s_{k-1} + P_k; Sprev packed
//           in-place over P (same LDS slot, same lane)
//   phase3: y[i][m] = sum_k W2[k][i] [x|Sprev][m][k]  (24 MFMA, K=192)
// Zero barriers; LDS double-buffered (2 x 4.4 KB) so group g+1's phase1 can
// overlap group g's phase3.
// ---------------------------------------------------------------------------
__global__ __launch_bounds__(64) void ks_kernel(
    const bf16* __restrict__ u, bf16* __restrict__ v,
    const bf16* __restrict__ Vp, const bf16* __restrict__ W2p,
    const float2* __restrict__ lamT)
{
    int bc = blockIdx.x;               // b*C + c
    int c  = bc & (CC - 1);
    int l  = threadIdx.x;              // lane: MFMA lane AND mode index n
    const bf16* xrow = u + (size_t)bc * LL;
    bf16*       vrow = v + (size_t)bc * LL;
    const bf16* Vpc  = Vp  + (size_t)c * 8192;
    const bf16* W2c  = W2p + (size_t)c * 12288;

    __shared__ short Sp[2 * 16 * 136];     // bf16 bits, 2 buffers, row=136

    const int mloc = l & 15;               // chunk-within-group (MFMA B-col)
    const int koff = (l >> 4) * 8;
    float2 lt = lamT[c * NN + l];
    float sr = 0.f, si = 0.f;              // running state, f32 entire L

#pragma unroll 2
    for (int g = 0; g < 4; ++g) {
        short* S = &Sp[(g & 1) * (16 * 136)];
        const bf16* xg = xrow + (g * 16 + mloc) * 64;
        short8 xf0 = *(const short8*)(xg + koff);
        short8 xf1 = *(const short8*)(xg + 32 + koff);

        // ---- phase 1 (two 4-nf halves to cap acc pressure) ----
#pragma unroll
        for (int h = 0; h < 2; ++h) {
            f32x4 acc[4];
#pragma unroll
            for (int j = 0; j < 4; ++j) acc[j] = (f32x4){0.f, 0.f, 0.f, 0.f};
#pragma unroll
            for (int j = 0; j < 4; ++j) {
                int nf = h * 4 + j;
                short8 vf0 = *(const short8*)(Vpc + ((nf * 2 + 0) * 64 + l) * 8);
                short8 vf1 = *(const short8*)(Vpc + ((nf * 2 + 1) * 64 + l) * 8);
                acc[j] = MFMA(vf0, xf0, acc[j]);
                acc[j] = MFMA(vf1, xf1, acc[j]);
            }
#pragma unroll
            for (int j = 0; j < 4; ++j) {
                int nf = h * 4 + j;
                short4v t;
                t[0] = bfbits(acc[j][0]); t[1] = bfbits(acc[j][1]);
                t[2] = bfbits(acc[j][2]); t[3] = bfbits(acc[j][3]);
                *(short4v*)(&S[mloc * 136 + nf * 16 + (l >> 4) * 4]) = t;
            }
        }
        asm volatile("" ::: "memory");     // same-wave DS pipe is in-order

        // ---- scan: 16 private steps; Sprev replaces P in place ----
#pragma unroll
        for (int k = 0; k < 16; ++k) {
            uint pk = *(const uint*)(&S[k * 136 + 2 * l]);
            union { short2 s2; uint uu; } o;
            o.s2.x = bfbits(sr); o.s2.y = bfbits(si);
            *(uint*)(&S[k * 136 + 2 * l]) = o.uu;      // Sprev for chunk k
            float pr = __uint_as_float(pk << 16);
            float pi = __uint_as_float(pk & 0xffff0000u);
            float nr = fmaf(lt.x, sr, fmaf(-lt.y, si, pr));
            si = fmaf(lt.x, si, fmaf(lt.y, sr, pi));
            sr = nr;
        }
        asm volatile("" ::: "memory");

        // ---- phase 3: K=192 GEMM over [x | Sprev] ----
        f32x4 o[4];
#pragma unroll
        for (int nf = 0; nf < 4; ++nf) o[nf] = (f32x4){0.f, 0.f, 0.f, 0.f};
#pragma unroll
        for (int ks = 0; ks < 6; ++ks) {
            short8 xf;
            if (ks == 0)      xf = xf0;
            else if (ks == 1) xf = xf1;
            else              xf = *(const short8*)(&S[mloc * 136 + (ks - 2) * 32 + koff]);
#pragma unroll
            for (int nf = 0; nf < 4; ++nf) {
                short8 wf = *(const short8*)(W2c + ((nf * 6 + ks) * 64 + l) * 8);
                o[nf] = MFMA(wf, xf, o[nf]);
            }
        }
#pragma unroll
        for (int nf = 0; nf < 4; ++nf) {
            short4v t;
            t[0] = bfbits(o[nf][0]); t[1] = bfbits(o[nf][1]);
            t[2] = bfbits(o[nf][2]); t[3] = bfbits(o[nf][3]);
            *(short4v*)(vrow + (g * 16 + mloc) * 64 + nf * 16 + (l >> 4) * 4) = t;
        }
    }
}

// ---------------------------------------------------------------------------
// LayerNorm over C (bf16 in/out); final layer fuses head projection (fp32).
// ---------------------------------------------------------------------------
__global__ __launch_bounds__(256) void ln_kernel(
    const bf16* __restrict__ v, bf16* __restrict__ outx,
    const float* __restrict__ w, const float* __restrict__ bta,
    const float* __restrict__ headw, const float* __restrict__ headb,
    float* __restrict__ fout, int isfinal)
{
    __shared__ float tile[CC][65];
    __shared__ float r1[4][64];
    __shared__ float r2[4][64];
    __shared__ float mrs[2][64];
    int b    = blockIdx.y;
    int l0   = blockIdx.x * 64;
    int lane = threadIdx.x & 63;
    int cg   = threadIdx.x >> 6;
    float sum = 0.0f, sq = 0.0f;
#pragma unroll
    for (int ci = 0; ci < 32; ++ci) {
        int c = cg * 32 + ci;
        float val = __bfloat162float(v[((size_t)b * CC + c) * LL + l0 + lane]);
        tile[c][lane] = val;
        sum += val;
        sq = fmaf(val, val, sq);
    }
    r1[cg][lane] = sum;
    r2[cg][lane] = sq;
    __syncthreads();
    if (cg == 0) {
        float s = r1[0][lane] + r1[1][lane] + r1[2][lane] + r1[3][lane];
        float q = r2[0][lane] + r2[1][lane] + r2[2][lane] + r2[3][lane];
        float mean = s * (1.0f / CC);
        float var  = q * (1.0f / CC) - mean * mean;
        mrs[0][lane] = mean;
        mrs[1][lane] = rsqrtf(var + EPSV);
    }
    __syncthreads();
    float mean = mrs[0][lane], rstd = mrs[1][lane];
    if (!isfinal) {
#pragma unroll
        for (int ci = 0; ci < 32; ++ci) {
            int c = cg * 32 + ci;
            float o = (tile[c][lane] - mean) * rstd * w[c] + bta[c];
            outx[((size_t)b * CC + c) * LL + l0 + lane] = tobf(o);
        }
    } else {
        float h = 0.0f;
#pragma unroll
        for (int ci = 0; ci < 32; ++ci) {
            int c = cg * 32 + ci;
            float o = (tile[c][lane] - mean) * rstd * w[c] + bta[c];
            h = fmaf(o, headw[c], h);
        }
        __syncthreads();
        r1[cg][lane] = h;
        __syncthreads();
        if (cg == 0)
            fout[(size_t)b * LL + l0 + lane] =
                r1[0][lane] + r1[1][lane] + r1[2][lane] + r1[3][lane] + headb[0];
    }
}

// ---------------------------------------------------------------------------
extern "C" void kernel_launch(void* const* d_in, const int* in_sizes, int n_in,
                              void* d_out, int out_size, void* d_ws, size_t ws_size,
                              hipStream_t stream)
{
    const float* x      = (const float*)d_in[0];
    const float* log_dt = (const float*)d_in[1];
    const float* A_real = (const float*)d_in[2];
    const float* A_imag = (const float*)d_in[3];
    const float* C_re   = (const float*)d_in[4];
    const float* C_im   = (const float*)d_in[5];
    const float* Dskip  = (const float*)d_in[6];
    const float* norm_w = (const float*)d_in[7];
    const float* norm_b = (const float*)d_in[8];
    const float* head_w = (const float*)d_in[9];
    const float* head_b = (const float*)d_in[10];
    float* out = (float*)d_out;

    const size_t DCN = (size_t)DEPTH_ * CC * NN;
    const size_t BCL = (size_t)BB * CC * LL;

    float2* lam  = (float2*)d_ws;
    float2* dta  = lam + DCN;
    float2* cb2  = dta + DCN;
    float2* lamT = cb2 + DCN;
    float*  Kloc = (float*)(lamT + DCN);
    bf16*   u    = (bf16*)(Kloc + (size_t)DEPTH_ * CC * 64);
    bf16*   v    = u + BCL;
    bf16*   Vp   = v + BCL;
    bf16*   W2p  = Vp + (size_t)DEPTH_ * CC * 8192;

    p0_kernel<<<dim3(CC, DEPTH_), 64, 0, stream>>>(
        log_dt, A_real, A_imag, C_re, C_im, lam, dta, cb2, lamT);
    p1_kernel<<<dim3(CC, DEPTH_), 64, 0, stream>>>(cb2, lam, Kloc);
    p2v_kernel<<<(DEPTH_ * CC * 8192) / 256, 256, 0, stream>>>(dta, Vp);
    p2w_kernel<<<(DEPTH_ * CC * 12288) / 256, 256, 0, stream>>>(
        dta, cb2, Kloc, Dskip, W2p);
    transpose_kernel<<<dim3(CC / 64, LL / 64, BB), 256, 0, stream>>>(x, u);

    for (int d = 0; d < DEPTH_; ++d) {
        ks_kernel<<<BB * CC, 64, 0, stream>>>(
            u, v, Vp + (size_t)d * CC * 8192, W2p + (size_t)d * CC * 12288,
            lamT + (size_t)d * CC * NN);
        ln_kernel<<<dim3(LL / 64, BB), 256, 0, stream>>>(
            v, u, norm_w + d * CC, norm_b + d * CC,
            head_w, head_b, out, (d == DEPTH_ - 1) ? 1 : 0);
    }
}